// Round 1
// baseline (1113.731 us; speedup 1.0000x reference)
//
#include <hip/hip_runtime.h>

// 3-layer GCN forward (PyG GCNConv semantics, eval mode).
// x:[N,4] f32, edge_index:[2,E] int32, W1[4,32] b1[32] W2[32,64] b2[64] W3[64,64] b3[64]
// out:[N,64] f32.
//
// Pipeline per layer: t = act(h) @ W  ->  acc = t*dinv^2 + b (self-loop+bias, full
// overwrite)  ->  scatter: acc[dst] += t[src]*dinv[src]*dinv[dst]  (atomicAdd).

#define TPB 256

__global__ __launch_bounds__(TPB) void deg_init(float* __restrict__ deg, int n) {
    int i = blockIdx.x * TPB + threadIdx.x;
    if (i < n) deg[i] = 1.0f;  // self-loop
}

__global__ __launch_bounds__(TPB) void deg_count(const int* __restrict__ dst,
                                                 float* __restrict__ deg, int e) {
    int i = blockIdx.x * TPB + threadIdx.x;
    if (i < e) atomicAdd(&deg[dst[i]], 1.0f);
}

__global__ __launch_bounds__(TPB) void deg_to_dinv(float* __restrict__ deg, int n) {
    int i = blockIdx.x * TPB + threadIdx.x;
    if (i < n) deg[i] = rsqrtf(deg[i]);  // deg >= 1 always
}

// t[i][c] = sum_k act(in[i][k]) * W[k][c]   (one thread per (i,c); W in LDS)
template <int K, int C, bool RELU_IN>
__global__ __launch_bounds__(TPB) void xw_kernel(const float* __restrict__ in,
                                                 const float* __restrict__ W,
                                                 float* __restrict__ out, int n) {
    __shared__ float sW[K * C];
    for (int t = threadIdx.x; t < K * C; t += TPB) sW[t] = W[t];
    __syncthreads();
    int idx = blockIdx.x * TPB + threadIdx.x;
    int i = idx / C, c = idx % C;  // C is pow2 -> shifts
    if (i >= n) return;
    float acc = 0.0f;
#pragma unroll
    for (int k = 0; k < K; ++k) {
        float v = in[i * K + k];
        if (RELU_IN) v = fmaxf(v, 0.0f);
        acc = fmaf(v, sW[k * C + c], acc);
    }
    out[i * C + c] = acc;
}

// acc[i][c] = t[i][c]*dinv[i]^2 + b[c]   (self-loop contribution + bias; FULL overwrite)
template <int C>
__global__ __launch_bounds__(TPB) void init_acc(const float* __restrict__ t,
                                                const float* __restrict__ dinv,
                                                const float* __restrict__ b,
                                                float* __restrict__ acc, int n) {
    int idx = blockIdx.x * TPB + threadIdx.x;
    int i = idx / C, c = idx % C;
    if (i >= n) return;
    float dv = dinv[i];
    acc[idx] = fmaf(t[idx], dv * dv, b[c]);
}

// acc[dst][c] += t[src][c] * dinv[src]*dinv[dst]   (64/32 consecutive lanes = one edge)
template <int C>
__global__ __launch_bounds__(TPB) void scatter_edges(const float* __restrict__ t,
                                                     const int* __restrict__ src,
                                                     const int* __restrict__ dst,
                                                     const float* __restrict__ dinv,
                                                     float* __restrict__ acc, int e) {
    int idx = blockIdx.x * TPB + threadIdx.x;
    int ei = idx / C, c = idx % C;
    if (ei >= e) return;
    int s = src[ei], d = dst[ei];
    float nrm = dinv[s] * dinv[d];
    atomicAdd(&acc[d * C + c], t[s * C + c] * nrm);
}

static inline int cdiv(long long a, int b) { return (int)((a + b - 1) / b); }

extern "C" void kernel_launch(void* const* d_in, const int* in_sizes, int n_in,
                              void* d_out, int out_size, void* d_ws, size_t ws_size,
                              hipStream_t stream) {
    const float* x  = (const float*)d_in[0];
    const int*   ei = (const int*)d_in[1];
    const float* W1 = (const float*)d_in[2];
    const float* b1 = (const float*)d_in[3];
    const float* W2 = (const float*)d_in[4];
    const float* b2 = (const float*)d_in[5];
    const float* W3 = (const float*)d_in[6];
    const float* b3 = (const float*)d_in[7];
    float* out = (float*)d_out;

    const int n = in_sizes[0] / 4;   // 100000
    const int e = in_sizes[1] / 2;   // 1600000
    const int* src = ei;
    const int* dst = ei + e;

    // workspace layout: dinv[n] | A[n*64] | B[n*64]
    char* ws = (char*)d_ws;
    float* dinv = (float*)ws;
    size_t off = ((size_t)n * sizeof(float) + 255) & ~(size_t)255;
    float* A = (float*)(ws + off);
    float* B = (float*)(ws + off + (size_t)n * 64 * sizeof(float));

    // --- degrees -> dinv ---
    deg_init<<<cdiv(n, TPB), TPB, 0, stream>>>(dinv, n);
    deg_count<<<cdiv(e, TPB), TPB, 0, stream>>>(dst, dinv, e);
    deg_to_dinv<<<cdiv(n, TPB), TPB, 0, stream>>>(dinv, n);

    // --- layer 1: C=32 ---
    xw_kernel<4, 32, false><<<cdiv((long long)n * 32, TPB), TPB, 0, stream>>>(x, W1, A, n);
    init_acc<32><<<cdiv((long long)n * 32, TPB), TPB, 0, stream>>>(A, dinv, b1, B, n);
    scatter_edges<32><<<cdiv((long long)e * 32, TPB), TPB, 0, stream>>>(A, src, dst, dinv, B, e);

    // --- layer 2: relu(B) @ W2, C=64 ---
    xw_kernel<32, 64, true><<<cdiv((long long)n * 64, TPB), TPB, 0, stream>>>(B, W2, A, n);
    init_acc<64><<<cdiv((long long)n * 64, TPB), TPB, 0, stream>>>(A, dinv, b2, B, n);
    scatter_edges<64><<<cdiv((long long)e * 64, TPB), TPB, 0, stream>>>(A, src, dst, dinv, B, e);

    // --- layer 3: relu(B) @ W3, C=64, accumulate into d_out ---
    xw_kernel<64, 64, true><<<cdiv((long long)n * 64, TPB), TPB, 0, stream>>>(B, W3, A, n);
    init_acc<64><<<cdiv((long long)n * 64, TPB), TPB, 0, stream>>>(A, dinv, b3, out, n);
    scatter_edges<64><<<cdiv((long long)e * 64, TPB), TPB, 0, stream>>>(A, src, dst, dinv, out, e);
}

// Round 2
// 567.467 us; speedup vs baseline: 1.9626x; 1.9626x over previous
//
#include <hip/hip_runtime.h>

// 3-layer GCN, pull-mode (CSR gather) + aggregate-before-transform.
//   A_norm @ (h W) == (A_norm @ h) W   -> aggregate at C_in (4/32/64 ch).
// Per layer: agg[i] = dinv[i]*( sum_{s in in(i)} h[s]*dinv[s] + h[i]*dinv[i] )
//            h_next = relu?( agg @ W + b )
// CSR by dst built once per call: histogram -> 3-kernel scan -> cursor fill.

#define TPB 256

static inline int cdiv(long long a, int b) { return (int)((a + b - 1) / b); }

// ---- degree / norm ----
__global__ __launch_bounds__(TPB) void zero2(int* __restrict__ a, int* __restrict__ b, int n) {
    int i = blockIdx.x * TPB + threadIdx.x;
    if (i < n) { a[i] = 0; b[i] = 0; }
}

__global__ __launch_bounds__(TPB) void hist_dst(const int* __restrict__ dst,
                                                int* __restrict__ cnt, int e) {
    int i = blockIdx.x * TPB + threadIdx.x;
    if (i < e) atomicAdd(&cnt[dst[i]], 1);
}

__global__ __launch_bounds__(TPB) void dinv_from_cnt(const int* __restrict__ cnt,
                                                     float* __restrict__ dinv, int n) {
    int i = blockIdx.x * TPB + threadIdx.x;
    if (i < n) dinv[i] = rsqrtf(1.0f + (float)cnt[i]);  // +1 self-loop
}

// ---- exclusive scan of cnt[n] -> rowptr (1024 elems/block) ----
__global__ __launch_bounds__(TPB) void scan1(const int* __restrict__ cnt,
                                             int* __restrict__ rowptr,
                                             int* __restrict__ bsum, int n) {
    __shared__ int lds[TPB];
    int tid = threadIdx.x;
    int base = blockIdx.x * 1024 + tid * 4;
    int v0 = base + 0 < n ? cnt[base + 0] : 0;
    int v1 = base + 1 < n ? cnt[base + 1] : 0;
    int v2 = base + 2 < n ? cnt[base + 2] : 0;
    int v3 = base + 3 < n ? cnt[base + 3] : 0;
    int t = v0 + v1 + v2 + v3;
    lds[tid] = t;
    __syncthreads();
    for (int off = 1; off < TPB; off <<= 1) {
        int x = (tid >= off) ? lds[tid - off] : 0;
        __syncthreads();
        lds[tid] += x;
        __syncthreads();
    }
    int excl = lds[tid] - t;
    if (tid == TPB - 1) bsum[blockIdx.x] = lds[TPB - 1];
    if (base + 0 < n) rowptr[base + 0] = excl;
    if (base + 1 < n) rowptr[base + 1] = excl + v0;
    if (base + 2 < n) rowptr[base + 2] = excl + v0 + v1;
    if (base + 3 < n) rowptr[base + 3] = excl + v0 + v1 + v2;
}

__global__ __launch_bounds__(TPB) void scan2(int* __restrict__ bsum, int nblk) {
    __shared__ int lds[TPB];
    int tid = threadIdx.x;
    int v = (tid < nblk) ? bsum[tid] : 0;
    lds[tid] = v;
    __syncthreads();
    for (int off = 1; off < TPB; off <<= 1) {
        int x = (tid >= off) ? lds[tid - off] : 0;
        __syncthreads();
        lds[tid] += x;
        __syncthreads();
    }
    if (tid < nblk) bsum[tid] = lds[tid] - v;  // exclusive
}

__global__ __launch_bounds__(TPB) void scan3(int* __restrict__ rowptr,
                                             const int* __restrict__ bsum, int n, int e) {
    int i = blockIdx.x * TPB + threadIdx.x;
    if (i < n) rowptr[i] += bsum[i >> 10];
    if (i == 0) rowptr[n] = e;
}

// ---- CSR fill ----
__global__ __launch_bounds__(TPB) void csr_fill(const int* __restrict__ src,
                                                const int* __restrict__ dst,
                                                const int* __restrict__ rowptr,
                                                int* __restrict__ cursor,
                                                int* __restrict__ csr, int e) {
    int i = blockIdx.x * TPB + threadIdx.x;
    if (i >= e) return;
    int d = dst[i];
    int pos = atomicAdd(&cursor[d], 1);
    csr[rowptr[d] + pos] = src[i];
}

// ---- aggregation: C lanes per node, register accumulate, one write ----
template <int C>
__global__ __launch_bounds__(TPB) void agg_kernel(const float* __restrict__ h,
                                                  const int* __restrict__ rowptr,
                                                  const int* __restrict__ csr,
                                                  const float* __restrict__ dinv,
                                                  float* __restrict__ agg, int n) {
    const int NPB = TPB / C;
    int grp = threadIdx.x / C, c = threadIdx.x % C;
    int i = blockIdx.x * NPB + grp;
    if (i >= n) return;
    float di = dinv[i];
    float acc = h[(size_t)i * C + c] * di;  // self-loop (x di again at the end -> di^2)
    int j = rowptr[i], re = rowptr[i + 1];
    int sNext = (j < re) ? csr[j] : 0;
    for (; j < re;) {
        int s = sNext;
        ++j;
        sNext = (j < re) ? csr[j] : 0;  // prefetch next index past the h/dinv loads
        acc = fmaf(h[(size_t)s * C + c], dinv[s], acc);
    }
    agg[(size_t)i * C + c] = acc * di;
}

// ---- dense transform: out[i][c] = relu?( sum_k in[i][k]*W[k][c] + b[c] ) ----
template <int K, int C, bool RELU_OUT>
__global__ __launch_bounds__(TPB) void xw_kernel(const float* __restrict__ in,
                                                 const float* __restrict__ W,
                                                 const float* __restrict__ b,
                                                 float* __restrict__ out, int n) {
    __shared__ float sW[K * C];
    for (int t = threadIdx.x; t < K * C; t += TPB) sW[t] = W[t];
    __syncthreads();
    int idx = blockIdx.x * TPB + threadIdx.x;
    int i = idx / C, c = idx % C;
    if (i >= n) return;
    float acc = b[c];
#pragma unroll
    for (int k = 0; k < K; ++k)
        acc = fmaf(in[(size_t)i * K + k], sW[k * C + c], acc);
    if (RELU_OUT) acc = fmaxf(acc, 0.0f);
    out[idx] = acc;
}

extern "C" void kernel_launch(void* const* d_in, const int* in_sizes, int n_in,
                              void* d_out, int out_size, void* d_ws, size_t ws_size,
                              hipStream_t stream) {
    const float* x  = (const float*)d_in[0];
    const int*   ei = (const int*)d_in[1];
    const float* W1 = (const float*)d_in[2];
    const float* b1 = (const float*)d_in[3];
    const float* W2 = (const float*)d_in[4];
    const float* b2 = (const float*)d_in[5];
    const float* W3 = (const float*)d_in[6];
    const float* b3 = (const float*)d_in[7];
    float* out = (float*)d_out;

    const int n = in_sizes[0] / 4;   // 100000
    const int e = in_sizes[1] / 2;   // 1600000
    const int* src = ei;
    const int* dst = ei + e;

    // ws layout (aligned 256): dinv[n] | rowptr[n+1] | cnt[n] | cursor[n] |
    //                          bsum[512] | csr[e] | A[n*64] | B[n*32]
    char* ws = (char*)d_ws;
    size_t off = 0;
    auto carve = [&](size_t bytes) {
        char* p = ws + off;
        off = (off + bytes + 255) & ~(size_t)255;
        return p;
    };
    float* dinv   = (float*)carve((size_t)n * 4);
    int*   rowptr = (int*)  carve((size_t)(n + 1) * 4);
    int*   cnt    = (int*)  carve((size_t)n * 4);
    int*   cursor = (int*)  carve((size_t)n * 4);
    int*   bsum   = (int*)  carve(512 * 4);
    int*   csr    = (int*)  carve((size_t)e * 4);
    float* A      = (float*)carve((size_t)n * 64 * 4);  // agg ping
    float* B      = (float*)carve((size_t)n * 32 * 4);  // h1
    // h2 lives in d_out (fully overwritten by xw3 afterwards)

    const int nblk_scan = cdiv(n, 1024);  // 98 (<=256)

    // ---- CSR + norms ----
    zero2<<<cdiv(n, TPB), TPB, 0, stream>>>(cnt, cursor, n);
    hist_dst<<<cdiv(e, TPB), TPB, 0, stream>>>(dst, cnt, e);
    dinv_from_cnt<<<cdiv(n, TPB), TPB, 0, stream>>>(cnt, dinv, n);
    scan1<<<nblk_scan, TPB, 0, stream>>>(cnt, rowptr, bsum, n);
    scan2<<<1, TPB, 0, stream>>>(bsum, nblk_scan);
    scan3<<<cdiv(n, TPB), TPB, 0, stream>>>(rowptr, bsum, n, e);
    csr_fill<<<cdiv(e, TPB), TPB, 0, stream>>>(src, dst, rowptr, cursor, csr, e);

    // ---- layer 1: agg(x) C=4 -> h1 = relu(agg@W1+b1) [n,32] ----
    agg_kernel<4><<<cdiv(n, TPB / 4), TPB, 0, stream>>>(x, rowptr, csr, dinv, A, n);
    xw_kernel<4, 32, true><<<cdiv((long long)n * 32, TPB), TPB, 0, stream>>>(A, W1, b1, B, n);

    // ---- layer 2: agg(h1) C=32 -> h2 = relu(agg@W2+b2) [n,64] (in d_out) ----
    agg_kernel<32><<<cdiv(n, TPB / 32), TPB, 0, stream>>>(B, rowptr, csr, dinv, A, n);
    xw_kernel<32, 64, true><<<cdiv((long long)n * 64, TPB), TPB, 0, stream>>>(A, W2, b2, out, n);

    // ---- layer 3: agg(h2) C=64 -> out = agg@W3+b3 ----
    agg_kernel<64><<<cdiv(n, TPB / 64), TPB, 0, stream>>>(out, rowptr, csr, dinv, A, n);
    xw_kernel<64, 64, false><<<cdiv((long long)n * 64, TPB), TPB, 0, stream>>>(A, W3, b3, out, n);
}

// Round 3
// 439.262 us; speedup vs baseline: 2.5355x; 1.2919x over previous
//
#include <hip/hip_runtime.h>

// 3-layer GCN, pull-mode CSR gather, aggregate-before-transform, prescaled features.
//   hs = h * dinv  (folded into producer);  agg[i] = dinv[i] * (sum_{s in N(i)} hs[s] + hs[i])
// Inner gather loop unrolled x8 for memory-level parallelism (latency-bound).

#define TPB 256

static inline int cdiv(long long a, int b) { return (int)((a + b - 1) / b); }

__global__ __launch_bounds__(TPB) void zero1(int* __restrict__ a, int n) {
    int i = blockIdx.x * TPB + threadIdx.x;
    if (i < n) a[i] = 0;
}

__global__ __launch_bounds__(TPB) void hist_dst(const int* __restrict__ dst,
                                                int* __restrict__ cnt, int e) {
    int i = blockIdx.x * TPB + threadIdx.x;
    if (i < e) atomicAdd(&cnt[dst[i]], 1);
}

__global__ __launch_bounds__(TPB) void dinv_from_cnt(const int* __restrict__ cnt,
                                                     float* __restrict__ dinv, int n) {
    int i = blockIdx.x * TPB + threadIdx.x;
    if (i < n) dinv[i] = rsqrtf(1.0f + (float)cnt[i]);  // +1 self-loop
}

// ---- exclusive scan of cnt[n] -> rowptr (1024 elems/block) ----
__global__ __launch_bounds__(TPB) void scan1(const int* __restrict__ cnt,
                                             int* __restrict__ rowptr,
                                             int* __restrict__ bsum, int n) {
    __shared__ int lds[TPB];
    int tid = threadIdx.x;
    int base = blockIdx.x * 1024 + tid * 4;
    int v0 = base + 0 < n ? cnt[base + 0] : 0;
    int v1 = base + 1 < n ? cnt[base + 1] : 0;
    int v2 = base + 2 < n ? cnt[base + 2] : 0;
    int v3 = base + 3 < n ? cnt[base + 3] : 0;
    int t = v0 + v1 + v2 + v3;
    lds[tid] = t;
    __syncthreads();
    for (int off = 1; off < TPB; off <<= 1) {
        int x = (tid >= off) ? lds[tid - off] : 0;
        __syncthreads();
        lds[tid] += x;
        __syncthreads();
    }
    int excl = lds[tid] - t;
    if (tid == TPB - 1) bsum[blockIdx.x] = lds[TPB - 1];
    if (base + 0 < n) rowptr[base + 0] = excl;
    if (base + 1 < n) rowptr[base + 1] = excl + v0;
    if (base + 2 < n) rowptr[base + 2] = excl + v0 + v1;
    if (base + 3 < n) rowptr[base + 3] = excl + v0 + v1 + v2;
}

__global__ __launch_bounds__(TPB) void scan2(int* __restrict__ bsum, int nblk) {
    __shared__ int lds[TPB];
    int tid = threadIdx.x;
    int v = (tid < nblk) ? bsum[tid] : 0;
    lds[tid] = v;
    __syncthreads();
    for (int off = 1; off < TPB; off <<= 1) {
        int x = (tid >= off) ? lds[tid - off] : 0;
        __syncthreads();
        lds[tid] += x;
        __syncthreads();
    }
    if (tid < nblk) bsum[tid] = lds[tid] - v;  // exclusive
}

__global__ __launch_bounds__(TPB) void scan3(int* __restrict__ rowptr,
                                             int* __restrict__ cursor,
                                             const int* __restrict__ bsum, int n, int e) {
    int i = blockIdx.x * TPB + threadIdx.x;
    if (i < n) {
        int r = rowptr[i] + bsum[i >> 10];
        rowptr[i] = r;
        cursor[i] = r;
    }
    if (i == 0) rowptr[n] = e;
}

__global__ __launch_bounds__(TPB) void csr_fill(const int* __restrict__ src,
                                                const int* __restrict__ dst,
                                                int* __restrict__ cursor,
                                                int* __restrict__ csr, int e) {
    int i = blockIdx.x * TPB + threadIdx.x;
    if (i >= e) return;
    int pos = atomicAdd(&cursor[dst[i]], 1);
    csr[pos] = src[i];
}

// xs[i][k] = x[i][k] * dinv[i]
template <int K>
__global__ __launch_bounds__(TPB) void prescale(const float* __restrict__ x,
                                                const float* __restrict__ dinv,
                                                float* __restrict__ xs, int n) {
    int idx = blockIdx.x * TPB + threadIdx.x;
    if (idx < n * K) xs[idx] = x[idx] * dinv[idx / K];
}

// ---- aggregation: C lanes per node, unroll-8 gather, one coalesced write ----
template <int C>
__global__ __launch_bounds__(TPB) void agg_kernel(const float* __restrict__ hs,
                                                  const int* __restrict__ rowptr,
                                                  const int* __restrict__ csr,
                                                  const float* __restrict__ dinv,
                                                  float* __restrict__ agg, int n) {
    const int NPB = TPB / C;
    int grp = threadIdx.x / C, c = threadIdx.x % C;
    int i = blockIdx.x * NPB + grp;
    if (i >= n) return;
    int j = rowptr[i], re = rowptr[i + 1];
    float acc = hs[(size_t)i * C + c];  // self-loop term
    float acc2 = 0.0f;
    for (; j + 8 <= re; j += 8) {
        int s0 = csr[j + 0], s1 = csr[j + 1], s2 = csr[j + 2], s3 = csr[j + 3];
        int s4 = csr[j + 4], s5 = csr[j + 5], s6 = csr[j + 6], s7 = csr[j + 7];
        float v0 = hs[(size_t)s0 * C + c], v1 = hs[(size_t)s1 * C + c];
        float v2 = hs[(size_t)s2 * C + c], v3 = hs[(size_t)s3 * C + c];
        float v4 = hs[(size_t)s4 * C + c], v5 = hs[(size_t)s5 * C + c];
        float v6 = hs[(size_t)s6 * C + c], v7 = hs[(size_t)s7 * C + c];
        acc  += (v0 + v1) + (v2 + v3);
        acc2 += (v4 + v5) + (v6 + v7);
    }
    if (j + 4 <= re) {
        int s0 = csr[j + 0], s1 = csr[j + 1], s2 = csr[j + 2], s3 = csr[j + 3];
        acc  += hs[(size_t)s0 * C + c] + hs[(size_t)s1 * C + c];
        acc2 += hs[(size_t)s2 * C + c] + hs[(size_t)s3 * C + c];
        j += 4;
    }
    for (; j < re; ++j) acc += hs[(size_t)csr[j] * C + c];
    agg[(size_t)i * C + c] = (acc + acc2) * dinv[i];
}

// ---- dense transform: out[i][c] = (relu?)( in[i]@W + b )[c] * (dinv[i] if SCALE) ----
template <int K, int C, bool RELU_OUT, bool SCALE_OUT>
__global__ __launch_bounds__(TPB) void xw_kernel(const float* __restrict__ in,
                                                 const float* __restrict__ W,
                                                 const float* __restrict__ b,
                                                 const float* __restrict__ dinv,
                                                 float* __restrict__ out, int n) {
    __shared__ float sW[K * C];
    for (int t = threadIdx.x; t < K * C; t += TPB) sW[t] = W[t];
    __syncthreads();
    int idx = blockIdx.x * TPB + threadIdx.x;
    int i = idx / C, c = idx % C;
    if (i >= n) return;
    float acc = b[c];
#pragma unroll
    for (int k = 0; k < K; ++k)
        acc = fmaf(in[(size_t)i * K + k], sW[k * C + c], acc);
    if (RELU_OUT) acc = fmaxf(acc, 0.0f);
    if (SCALE_OUT) acc *= dinv[i];
    out[idx] = acc;
}

extern "C" void kernel_launch(void* const* d_in, const int* in_sizes, int n_in,
                              void* d_out, int out_size, void* d_ws, size_t ws_size,
                              hipStream_t stream) {
    const float* x  = (const float*)d_in[0];
    const int*   ei = (const int*)d_in[1];
    const float* W1 = (const float*)d_in[2];
    const float* b1 = (const float*)d_in[3];
    const float* W2 = (const float*)d_in[4];
    const float* b2 = (const float*)d_in[5];
    const float* W3 = (const float*)d_in[6];
    const float* b3 = (const float*)d_in[7];
    float* out = (float*)d_out;

    const int n = in_sizes[0] / 4;   // 100000
    const int e = in_sizes[1] / 2;   // 1600000
    const int* src = ei;
    const int* dst = ei + e;

    char* ws = (char*)d_ws;
    size_t off = 0;
    auto carve = [&](size_t bytes) {
        char* p = ws + off;
        off = (off + bytes + 255) & ~(size_t)255;
        return p;
    };
    float* dinv   = (float*)carve((size_t)n * 4);
    int*   rowptr = (int*)  carve((size_t)(n + 1) * 4);
    int*   cnt    = (int*)  carve((size_t)n * 4);
    int*   cursor = (int*)  carve((size_t)n * 4);
    int*   bsum   = (int*)  carve(512 * 4);
    int*   csr    = (int*)  carve((size_t)e * 4);
    float* A      = (float*)carve((size_t)n * 64 * 4);  // agg output
    float* B      = (float*)carve((size_t)n * 32 * 4);  // h1s
    float* xs     = (float*)carve((size_t)n * 4 * 4);   // prescaled x
    // h2s lives in d_out (fully overwritten by final xw)

    const int nblk_scan = cdiv(n, 1024);

    // ---- CSR + norms ----
    zero1<<<cdiv(n, TPB), TPB, 0, stream>>>(cnt, n);
    hist_dst<<<cdiv(e, TPB), TPB, 0, stream>>>(dst, cnt, e);
    dinv_from_cnt<<<cdiv(n, TPB), TPB, 0, stream>>>(cnt, dinv, n);
    scan1<<<nblk_scan, TPB, 0, stream>>>(cnt, rowptr, bsum, n);
    scan2<<<1, TPB, 0, stream>>>(bsum, nblk_scan);
    scan3<<<cdiv(n, TPB), TPB, 0, stream>>>(rowptr, cursor, bsum, n, e);
    csr_fill<<<cdiv(e, TPB), TPB, 0, stream>>>(src, dst, cursor, csr, e);

    // ---- layer 1: xs = x*dinv; agg C=4; h1s = relu(agg@W1+b1)*dinv [n,32] ----
    prescale<4><<<cdiv((long long)n * 4, TPB), TPB, 0, stream>>>(x, dinv, xs, n);
    agg_kernel<4><<<cdiv(n, TPB / 4), TPB, 0, stream>>>(xs, rowptr, csr, dinv, A, n);
    xw_kernel<4, 32, true, true><<<cdiv((long long)n * 32, TPB), TPB, 0, stream>>>(A, W1, b1, dinv, B, n);

    // ---- layer 2: agg C=32; h2s = relu(agg@W2+b2)*dinv [n,64] (in d_out) ----
    agg_kernel<32><<<cdiv(n, TPB / 32), TPB, 0, stream>>>(B, rowptr, csr, dinv, A, n);
    xw_kernel<32, 64, true, true><<<cdiv((long long)n * 64, TPB), TPB, 0, stream>>>(A, W2, b2, dinv, out, n);

    // ---- layer 3: agg C=64; out = agg@W3+b3 ----
    agg_kernel<64><<<cdiv(n, TPB / 64), TPB, 0, stream>>>(out, rowptr, csr, dinv, A, n);
    xw_kernel<64, 64, false, false><<<cdiv((long long)n * 64, TPB), TPB, 0, stream>>>(A, W3, b3, dinv, out, n);
}